// Round 8
// baseline (583.554 us; speedup 1.0000x reference)
//
#include <hip/hip_runtime.h>

#define D 128
#define BSH 8                    // bucket = dst >> BSH (256 nodes per bucket)
#define BNODES (1 << BSH)
#define NCHUNK 512               // edge chunks; grid of place/hist kernels
#define MAXB 512                 // LDS bucket-array capacity (NBKT <= 512, N <= 131072)

typedef __attribute__((ext_vector_type(8))) __bf16 bf16x8;
typedef __attribute__((ext_vector_type(4))) float f32x4;

__device__ __forceinline__ unsigned short f2bf(float f) {
    unsigned int u = __float_as_uint(f);
    u += 0x7fffu + ((u >> 16) & 1u);  // round-to-nearest-even
    return (unsigned short)(u >> 16);
}
// bf16 pair packed in u32 (lo = even feature, hi = odd feature)
__device__ __forceinline__ float lo_f(unsigned u) { return __uint_as_float(u << 16); }
__device__ __forceinline__ float hi_f(unsigned u) { return __uint_as_float(u & 0xffff0000u); }

// ---------------- CSR build: contention-free counting sort ----------------
// pairs layout: (dstLocal<<24) | src   (needs N < 2^24, BNODES <= 256)

__global__ __launch_bounds__(256) void k_hist(const int* __restrict__ dst,
                                              int* __restrict__ cnts,
                                              int E, int nbkt, int chunk) {
    __shared__ int hist[MAXB];
    int c = blockIdx.x;
    int t = threadIdx.x;
    for (int i = t; i < nbkt; i += 256) hist[i] = 0;
    __syncthreads();
    int e0 = c * chunk, e1 = min(e0 + chunk, E);
    for (int e = e0 + t; e < e1; e += 256) atomicAdd(&hist[dst[e] >> BSH], 1);
    __syncthreads();
    for (int i = t; i < nbkt; i += 256) cnts[(size_t)i * NCHUNK + c] = hist[i];
}

// one wave per bucket: exclusive scan over the NCHUNK chunk-counts (in place),
// bucket total -> btot[b]. cnts reads/writes are lane-coalesced.
__global__ __launch_bounds__(256) void k_chunksum(int* __restrict__ cnts,
                                                  int* __restrict__ btot, int nbkt) {
    int b = blockIdx.x * 4 + (threadIdx.x >> 6);
    if (b >= nbkt) return;
    int l = threadIdx.x & 63;
    int carry = 0;
    for (int g = 0; g < NCHUNK; g += 64) {
        int v = cnts[(size_t)b * NCHUNK + g + l];
        int x = v;
#pragma unroll
        for (int off = 1; off < 64; off <<= 1) {
            int u = __shfl_up(x, off);
            if (l >= off) x += u;
        }
        cnts[(size_t)b * NCHUNK + g + l] = carry + x - v;  // exclusive
        carry += __shfl(x, 63);
    }
    if (l == 0) btot[b] = carry;
}

// one block: exclusive scan of bucket totals -> bbase[0..nbkt] (bbase[nbkt] = E)
__global__ __launch_bounds__(MAXB) void k_bktscan(const int* __restrict__ btot,
                                                  int* __restrict__ bbase, int nbkt) {
    __shared__ int s[MAXB];
    int t = threadIdx.x;
    int v = (t < nbkt) ? btot[t] : 0;
    s[t] = v;
    __syncthreads();
    for (int off = 1; off < MAXB; off <<= 1) {
        int u = (t >= off) ? s[t - off] : 0;
        __syncthreads();
        s[t] += u;
        __syncthreads();
    }
    if (t < nbkt) bbase[t + 1] = s[t];
    if (t == 0) bbase[0] = 0;
}

// chunk c: place packed pairs at precomputed per-(chunk,bucket) offsets;
// cursors advance via LDS atomics only.
__global__ __launch_bounds__(256) void k_place(const int* __restrict__ src,
                                               const int* __restrict__ dst,
                                               const int* __restrict__ cnts,
                                               const int* __restrict__ bbase,
                                               unsigned* __restrict__ pairs,
                                               int E, int nbkt, int chunk) {
    __shared__ int cur[MAXB];
    int c = blockIdx.x;
    int t = threadIdx.x;
    for (int i = t; i < nbkt; i += 256)
        cur[i] = bbase[i] + cnts[(size_t)i * NCHUNK + c];
    __syncthreads();
    int e0 = c * chunk, e1 = min(e0 + chunk, E);
    for (int e = e0 + t; e < e1; e += 256) {
        int d = dst[e];
        int p = atomicAdd(&cur[d >> BSH], 1);
        pairs[p] = ((unsigned)(d & (BNODES - 1)) << 24) | (unsigned)src[e];
    }
}

// one block per bucket: derive per-node degree (LDS count over pairs), LDS scan
// -> rp + dinv + local cursors, then scatter col within the bucket's region.
__global__ __launch_bounds__(BNODES) void k_build(const unsigned* __restrict__ pairs,
                                                  const int* __restrict__ bbase,
                                                  int* __restrict__ rp,
                                                  float* __restrict__ dinv,
                                                  int* __restrict__ col, int N) {
    __shared__ int cntL[BNODES];
    __shared__ int lcur[BNODES];
    int b = blockIdx.x;
    int n0 = b << BSH;
    int t = threadIdx.x;
    int e0 = bbase[b], e1 = bbase[b + 1];

    cntL[t] = 0;
    __syncthreads();
    for (int e = e0 + t; e < e1; e += BNODES)
        atomicAdd(&cntL[pairs[e] >> 24], 1);
    __syncthreads();
    int deg = cntL[t];
    // inclusive scan of cntL (Hillis-Steele, in place)
    for (int off = 1; off < BNODES; off <<= 1) {
        int u = (t >= off) ? cntL[t - off] : 0;
        __syncthreads();
        cntL[t] += u;
        __syncthreads();
    }
    int rpv = e0 + cntL[t] - deg;  // exclusive + bucket base
    lcur[t] = rpv;
    int node = n0 + t;
    if (node < N) {
        rp[node] = rpv;
        dinv[node] = rsqrtf((float)deg + 1.0f);  // +1 self-loop
        if (node == N - 1) rp[N] = e1;
    }
    __syncthreads();
    for (int e = e0 + t; e < e1; e += BNODES) {
        unsigned v = pairs[e];
        int p = atomicAdd(&lcur[v >> 24], 1);
        col[p] = (int)(v & 0x00FFFFFFu);
    }
}

// ---------------- x f32 [n][128] -> ys bf16 SLICED, pre-scaled by dinv ------
// sliced layout: slice p (0..7) = features [16p,16p+16) of all nodes,
// node-contiguous 32B: u16 addr = ((p*N + n)*16 + f_in_slice)
__global__ __launch_bounds__(256) void k_cvt(const float* __restrict__ x,
                                             const float* __restrict__ dinv,
                                             unsigned short* __restrict__ ys, int N) {
    __shared__ unsigned As[64][65];  // [node][u32 pair]
    int t = threadIdx.x;
    int n0 = blockIdx.x * 64;
#pragma unroll
    for (int i = 0; i < 8; ++i) {
        int idx = i * 256 + t;  // float4 index within the 64x128 tile
        int r = idx >> 5;
        int c4 = idx & 31;
        if (n0 + r < N) {
            float4 v = reinterpret_cast<const float4*>(x)[(size_t)(n0 + r) * 32 + c4];
            float s = dinv[n0 + r];
            As[r][c4 * 2]     = ((unsigned)f2bf(v.y * s) << 16) | (unsigned)f2bf(v.x * s);
            As[r][c4 * 2 + 1] = ((unsigned)f2bf(v.w * s) << 16) | (unsigned)f2bf(v.z * s);
        }
    }
    __syncthreads();
    int r = t >> 2, j = t & 3;
    if (n0 + r < N) {
#pragma unroll
        for (int p = 0; p < 8; ++p) {
            uint2 w2 = make_uint2(As[r][p * 8 + 2 * j], As[r][p * 8 + 2 * j + 1]);
            reinterpret_cast<uint2*>(ys)[((size_t)p * N + n0 + r) * 4 + j] = w2;
        }
    }
}

// ---------------- W f32 -> Wt bf16 transposed (Wt[c][k] = W[k][c]) ----------
__global__ __launch_bounds__(256) void k_wcvt(const float* __restrict__ W1,
                                              const float* __restrict__ W2,
                                              unsigned short* __restrict__ Wt1,
                                              unsigned short* __restrict__ Wt2) {
    int idx = blockIdx.x * 256 + threadIdx.x;  // 0 .. 32767
    const float* W = (idx < 16384) ? W1 : W2;
    unsigned short* Wt = (idx < 16384) ? Wt1 : Wt2;
    int i = idx & 16383;
    int c = i >> 7, k = i & 127;
    Wt[(size_t)c * 128 + k] = f2bf(W[(size_t)k * 128 + c]);
}

// ---------------- sliced normalized aggregation (gather, L2-resident) -------
// One kernel launch covers 8 passes; pass = blockIdx.x / nblk (x-major dispatch
// keeps one ~3.2MB slice hot per XCD L2 at a time; perf-only assumption).
// Per pass/node (one wave): lane = (edge group g = l>>3, feature pair f = l&7).
// os[p][n][f] = bf16(dinv[n] * (ys[p][n][f] + sum_e ys[p][col[e]][f]))
__global__ __launch_bounds__(256) void k_aggs(const unsigned* __restrict__ ys,
                                              unsigned* __restrict__ os,
                                              const int* __restrict__ col,
                                              const int* __restrict__ rp,
                                              const float* __restrict__ dinv,
                                              int N, int nblk) {
    int pass = blockIdx.x / nblk;
    int node = (blockIdx.x - pass * nblk) * 4 + (threadIdx.x >> 6);
    if (node >= N) return;
    int l = threadIdx.x & 63;
    int g = l >> 3;
    int f = l & 7;
    const unsigned* base = ys + (size_t)pass * N * 8;

    float a0 = 0.0f, a1 = 0.0f;
    int e0 = rp[node], e1 = rp[node + 1];
    int e = e0 + g;
    for (; e + 8 < e1; e += 16) {  // unroll x2 (2 gathers in flight)
        int s0 = col[e], s1 = col[e + 8];
        unsigned u0 = base[(size_t)s0 * 8 + f];
        unsigned u1 = base[(size_t)s1 * 8 + f];
        a0 += lo_f(u0) + lo_f(u1);
        a1 += hi_f(u0) + hi_f(u1);
    }
    if (e < e1) {
        unsigned u = base[(size_t)col[e] * 8 + f];
        a0 += lo_f(u);
        a1 += hi_f(u);
    }
#pragma unroll
    for (int m = 8; m < 64; m <<= 1) {  // reduce the 8 edge-groups
        a0 += __shfl_xor(a0, m);
        a1 += __shfl_xor(a1, m);
    }
    if (g == 0) {
        unsigned v = base[(size_t)node * 8 + f];  // self loop
        a0 += lo_f(v);
        a1 += hi_f(v);
        float dn = dinv[node];
        os[(size_t)pass * N * 8 + (size_t)node * 8 + f] =
            ((unsigned)f2bf(a1 * dn) << 16) | (unsigned)f2bf(a0 * dn);
    }
}

// ---------------- MFMA GEMM + bias + relu (bf16 sliced A, f32 acc) ----------
// A sliced bf16 (agg output). 256 thr = 4 waves; wave: 32 rows x 128 cols.
// STORE_BF16=1: out bf16 SLICED (slice = nf, feat-in-slice = lr), dinv-scaled.
// STORE_BF16=0: out_f32[r][c] = relu(acc+bias), row-major.
// C/D mapping (HW-verified): col = lane&15, row = (lane>>4)*4 + reg.
template <int STORE_BF16>
__global__ __launch_bounds__(256) void k_mfma(const unsigned short* __restrict__ A,
                                              const unsigned short* __restrict__ Wt,
                                              const float* __restrict__ bias,
                                              float* __restrict__ out_f32,
                                              unsigned short* __restrict__ out_bf16,
                                              const float* __restrict__ dinv, int N) {
    int tid = threadIdx.x;
    int wv = tid >> 6, l = tid & 63;
    int lr = l & 15, lg = l >> 4;
    int r0 = blockIdx.x * 128 + wv * 32;

    f32x4 acc[2][8];
#pragma unroll
    for (int mi = 0; mi < 2; ++mi)
#pragma unroll
        for (int nf = 0; nf < 8; ++nf) acc[mi][nf] = (f32x4)(0.0f);

#pragma unroll
    for (int k0 = 0; k0 < 128; k0 += 32) {
        int p = (k0 >> 4) + (lg >> 1);   // slice holding features k0+lg*8..+8
        int hoff = (lg & 1) * 8;
        bf16x8 a[2];
#pragma unroll
        for (int mi = 0; mi < 2; ++mi) {
            int r = r0 + mi * 16 + lr;
            if (r >= N) r = N - 1;  // clamp: loads valid, stores guarded
            a[mi] = *reinterpret_cast<const bf16x8*>(&A[((size_t)p * N + r) * 16 + hoff]);
        }
#pragma unroll
        for (int nf = 0; nf < 8; ++nf) {
            bf16x8 b = *reinterpret_cast<const bf16x8*>(
                &Wt[(size_t)(nf * 16 + lr) * 128 + k0 + lg * 8]);
            acc[0][nf] = __builtin_amdgcn_mfma_f32_16x16x32_bf16(a[0], b, acc[0][nf], 0, 0, 0);
            acc[1][nf] = __builtin_amdgcn_mfma_f32_16x16x32_bf16(a[1], b, acc[1][nf], 0, 0, 0);
        }
    }

    float bv[8];
#pragma unroll
    for (int nf = 0; nf < 8; ++nf) bv[nf] = bias[nf * 16 + lr];

#pragma unroll
    for (int mi = 0; mi < 2; ++mi) {
#pragma unroll
        for (int q = 0; q < 4; ++q) {
            int r = r0 + mi * 16 + lg * 4 + q;
            if (r < N) {
                float dv = 1.0f;
                if (STORE_BF16) dv = dinv[r];
#pragma unroll
                for (int nf = 0; nf < 8; ++nf) {
                    float vv = fmaxf(acc[mi][nf][q] + bv[nf], 0.0f);
                    if (STORE_BF16)
                        out_bf16[((size_t)nf * N + r) * 16 + lr] = f2bf(vv * dv);
                    else
                        out_f32[(size_t)r * 128 + nf * 16 + lr] = vv;
                }
            }
        }
    }
}

// ---------------- launch ----------------

extern "C" void kernel_launch(void* const* d_in, const int* in_sizes, int n_in,
                              void* d_out, int out_size, void* d_ws, size_t ws_size,
                              hipStream_t stream) {
    const float* x  = (const float*)d_in[0];
    const int*   ei = (const int*)d_in[1];
    const float* W1 = (const float*)d_in[2];
    const float* b1 = (const float*)d_in[3];
    const float* W2 = (const float*)d_in[4];
    const float* b2 = (const float*)d_in[5];
    float* out = (float*)d_out;

    const int N = in_sizes[0] / D;
    const int E = in_sizes[1] / 2;
    const int* src = ei;
    const int* dst = ei + E;
    const int NBKT = (N + BNODES - 1) >> BSH;     // 391 for N=100000 (<= MAXB)
    const int CHUNK = (E + NCHUNK - 1) / NCHUNK;  // 3125 for E=1.6M

    char* w = (char*)d_ws;
    auto alloc = [&](size_t bytes) -> void* {
        void* p = (void*)w;
        w += (bytes + 255) & ~(size_t)255;
        return p;
    };
    float* dinv     = (float*)alloc((size_t)N * 4);
    int* rp         = (int*)alloc((size_t)(N + 1) * 4);
    int* cnts       = (int*)alloc((size_t)NBKT * NCHUNK * 4);  // ~0.8 MB
    int* btot       = (int*)alloc((size_t)NBKT * 4);
    int* bbase      = (int*)alloc((size_t)(NBKT + 1) * 4);
    unsigned* pairs = (unsigned*)alloc((size_t)E * 4);
    int* col        = (int*)alloc((size_t)E * 4);
    unsigned short* ys  = (unsigned short*)alloc((size_t)N * D * 2);  // sliced
    unsigned short* as_ = (unsigned short*)alloc((size_t)N * D * 2);  // sliced agg out
    unsigned short* y2s = (unsigned short*)alloc((size_t)N * D * 2);  // sliced layer-1 out
    unsigned short* Wt1 = (unsigned short*)alloc((size_t)D * D * 2);
    unsigned short* Wt2 = (unsigned short*)alloc((size_t)D * D * 2);

    k_hist<<<NCHUNK, 256, 0, stream>>>(dst, cnts, E, NBKT, CHUNK);
    k_chunksum<<<(NBKT + 3) / 4, 256, 0, stream>>>(cnts, btot, NBKT);
    k_bktscan<<<1, MAXB, 0, stream>>>(btot, bbase, NBKT);
    k_place<<<NCHUNK, 256, 0, stream>>>(src, dst, cnts, bbase, pairs, E, NBKT, CHUNK);
    k_build<<<NBKT, BNODES, 0, stream>>>(pairs, bbase, rp, dinv, col, N);
    k_wcvt<<<128, 256, 0, stream>>>(W1, W2, Wt1, Wt2);

    const int nblk = (N + 3) / 4;           // agg blocks per pass
    const int cvtblocks = (N + 63) / 64;
    const int gemmblocks = (N + 127) / 128;

    // layer 1: ys = sliced bf16(dinv*x); as_ = agg(ys); y2s = bf16(dinv*relu(as_@W1+b1))
    k_cvt<<<cvtblocks, 256, 0, stream>>>(x, dinv, ys, N);
    k_aggs<<<nblk * 8, 256, 0, stream>>>((const unsigned*)ys, (unsigned*)as_,
                                         col, rp, dinv, N, nblk);
    k_mfma<1><<<gemmblocks, 256, 0, stream>>>(as_, Wt1, b1, nullptr, y2s, dinv, N);
    // layer 2: as_ = agg(y2s); out = relu(as_@W2+b2) f32
    k_aggs<<<nblk * 8, 256, 0, stream>>>((const unsigned*)y2s, (unsigned*)as_,
                                         col, rp, dinv, N, nblk);
    k_mfma<0><<<gemmblocks, 256, 0, stream>>>(as_, Wt2, b2, out, nullptr, dinv, N);
}

// Round 9
// 246.221 us; speedup vs baseline: 2.3700x; 2.3700x over previous
//
#include <hip/hip_runtime.h>

#define D 128
#define BSH 8                    // bucket = dst >> BSH (256 nodes per bucket)
#define BNODES (1 << BSH)
#define NCHUNK 512               // edge chunks; grid of place/hist kernels
#define MAXB 512                 // LDS bucket-array capacity (NBKT <= 512, N <= 131072)

typedef __attribute__((ext_vector_type(8))) __bf16 bf16x8;
typedef __attribute__((ext_vector_type(4))) float f32x4;

__device__ __forceinline__ unsigned short f2bf(float f) {
    unsigned int u = __float_as_uint(f);
    u += 0x7fffu + ((u >> 16) & 1u);  // round-to-nearest-even
    return (unsigned short)(u >> 16);
}
// bf16 pair packed in u32 (lo = even feature, hi = odd feature)
__device__ __forceinline__ float lo_f(unsigned u) { return __uint_as_float(u << 16); }
__device__ __forceinline__ float hi_f(unsigned u) { return __uint_as_float(u & 0xffff0000u); }

// ---------------- CSR build: contention-free counting sort ----------------
// pairs layout: (dstLocal<<24) | src   (needs N < 2^24, BNODES <= 256)

__global__ __launch_bounds__(256) void k_hist(const int* __restrict__ dst,
                                              int* __restrict__ cnts,
                                              int E, int nbkt, int chunk) {
    __shared__ int hist[MAXB];
    int c = blockIdx.x;
    int t = threadIdx.x;
    for (int i = t; i < nbkt; i += 256) hist[i] = 0;
    __syncthreads();
    int e0 = c * chunk, e1 = min(e0 + chunk, E);
    for (int e = e0 + t; e < e1; e += 256) atomicAdd(&hist[dst[e] >> BSH], 1);
    __syncthreads();
    for (int i = t; i < nbkt; i += 256) cnts[(size_t)i * NCHUNK + c] = hist[i];
}

// one wave per bucket: exclusive scan over the NCHUNK chunk-counts (in place),
// bucket total -> btot[b]. cnts reads/writes are lane-coalesced.
__global__ __launch_bounds__(256) void k_chunksum(int* __restrict__ cnts,
                                                  int* __restrict__ btot, int nbkt) {
    int b = blockIdx.x * 4 + (threadIdx.x >> 6);
    if (b >= nbkt) return;
    int l = threadIdx.x & 63;
    int carry = 0;
    for (int g = 0; g < NCHUNK; g += 64) {
        int v = cnts[(size_t)b * NCHUNK + g + l];
        int x = v;
#pragma unroll
        for (int off = 1; off < 64; off <<= 1) {
            int u = __shfl_up(x, off);
            if (l >= off) x += u;
        }
        cnts[(size_t)b * NCHUNK + g + l] = carry + x - v;  // exclusive
        carry += __shfl(x, 63);
    }
    if (l == 0) btot[b] = carry;
}

// one block: exclusive scan of bucket totals -> bbase[0..nbkt] (bbase[nbkt] = E)
__global__ __launch_bounds__(MAXB) void k_bktscan(const int* __restrict__ btot,
                                                  int* __restrict__ bbase, int nbkt) {
    __shared__ int s[MAXB];
    int t = threadIdx.x;
    int v = (t < nbkt) ? btot[t] : 0;
    s[t] = v;
    __syncthreads();
    for (int off = 1; off < MAXB; off <<= 1) {
        int u = (t >= off) ? s[t - off] : 0;
        __syncthreads();
        s[t] += u;
        __syncthreads();
    }
    if (t < nbkt) bbase[t + 1] = s[t];
    if (t == 0) bbase[0] = 0;
}

// chunk c: place packed pairs at precomputed per-(chunk,bucket) offsets;
// cursors advance via LDS atomics only.
__global__ __launch_bounds__(256) void k_place(const int* __restrict__ src,
                                               const int* __restrict__ dst,
                                               const int* __restrict__ cnts,
                                               const int* __restrict__ bbase,
                                               unsigned* __restrict__ pairs,
                                               int E, int nbkt, int chunk) {
    __shared__ int cur[MAXB];
    int c = blockIdx.x;
    int t = threadIdx.x;
    for (int i = t; i < nbkt; i += 256)
        cur[i] = bbase[i] + cnts[(size_t)i * NCHUNK + c];
    __syncthreads();
    int e0 = c * chunk, e1 = min(e0 + chunk, E);
    for (int e = e0 + t; e < e1; e += 256) {
        int d = dst[e];
        int p = atomicAdd(&cur[d >> BSH], 1);
        pairs[p] = ((unsigned)(d & (BNODES - 1)) << 24) | (unsigned)src[e];
    }
}

// one block per bucket: derive per-node degree (LDS count over pairs), LDS scan
// -> rp + dinv + local cursors, then scatter col within the bucket's region.
__global__ __launch_bounds__(BNODES) void k_build(const unsigned* __restrict__ pairs,
                                                  const int* __restrict__ bbase,
                                                  int* __restrict__ rp,
                                                  float* __restrict__ dinv,
                                                  int* __restrict__ col, int N) {
    __shared__ int cntL[BNODES];
    __shared__ int lcur[BNODES];
    int b = blockIdx.x;
    int n0 = b << BSH;
    int t = threadIdx.x;
    int e0 = bbase[b], e1 = bbase[b + 1];

    cntL[t] = 0;
    __syncthreads();
    for (int e = e0 + t; e < e1; e += BNODES)
        atomicAdd(&cntL[pairs[e] >> 24], 1);
    __syncthreads();
    int deg = cntL[t];
    // inclusive scan of cntL (Hillis-Steele, in place)
    for (int off = 1; off < BNODES; off <<= 1) {
        int u = (t >= off) ? cntL[t - off] : 0;
        __syncthreads();
        cntL[t] += u;
        __syncthreads();
    }
    int rpv = e0 + cntL[t] - deg;  // exclusive + bucket base
    lcur[t] = rpv;
    int node = n0 + t;
    if (node < N) {
        rp[node] = rpv;
        dinv[node] = rsqrtf((float)deg + 1.0f);  // +1 self-loop
        if (node == N - 1) rp[N] = e1;
    }
    __syncthreads();
    for (int e = e0 + t; e < e1; e += BNODES) {
        unsigned v = pairs[e];
        int p = atomicAdd(&lcur[v >> 24], 1);
        col[p] = (int)(v & 0x00FFFFFFu);
    }
}

// ---------------- x -> bf16, pre-scaled by dinv[row] ----------------
__global__ __launch_bounds__(256) void k_cvt(const float* __restrict__ x,
                                             const float* __restrict__ dinv,
                                             unsigned short* __restrict__ y, int nchunk) {
    int g = blockIdx.x * blockDim.x + threadIdx.x;
    if (g >= nchunk) return;
    int row = g >> 5;  // 32 chunks of 4 per 128-wide row
    float s = dinv[row];
    float4 v = reinterpret_cast<const float4*>(x)[g];
    ushort4 o;
    o.x = f2bf(v.x * s);
    o.y = f2bf(v.y * s);
    o.z = f2bf(v.z * s);
    o.w = f2bf(v.w * s);
    reinterpret_cast<ushort4*>(y)[g] = o;
}

// ---------------- W f32 -> Wt bf16 transposed (Wt[c][k] = W[k][c]) ----------
__global__ __launch_bounds__(256) void k_wcvt(const float* __restrict__ W1,
                                              const float* __restrict__ W2,
                                              unsigned short* __restrict__ Wt1,
                                              unsigned short* __restrict__ Wt2) {
    int idx = blockIdx.x * 256 + threadIdx.x;  // 0 .. 32767
    const float* W = (idx < 16384) ? W1 : W2;
    unsigned short* Wt = (idx < 16384) ? Wt1 : Wt2;
    int i = idx & 16383;
    int c = i >> 7, k = i & 127;
    Wt[(size_t)c * 128 + k] = f2bf(W[(size_t)k * 128 + c]);
}

// ---------------- normalized aggregation (gather, bf16 rows) ----------------
// outp[n] (bf16 pairs) = bf16( dinv[n] * ( y[n] + sum_{e in CSR(n)} y[col[e]] ) )
// One wave64 per node; lane owns a bf16 feature pair (u32); edge loop unrolled
// x16 to maximize outstanding gathers (concurrency-bound at the fabric).
__global__ __launch_bounds__(256) void k_agg(const unsigned short* __restrict__ y,
                                             unsigned* __restrict__ outp,
                                             const int* __restrict__ col,
                                             const int* __restrict__ rp,
                                             const float* __restrict__ dinv, int n) {
    int node = blockIdx.x * 4 + (threadIdx.x >> 6);
    if (node >= n) return;
    int c = threadIdx.x & 63;  // feature pair index
    const unsigned* yv = reinterpret_cast<const unsigned*>(y);

    unsigned v = yv[(size_t)node * 64 + c];  // self loop
    float a0 = lo_f(v), a1 = hi_f(v);

    int e0 = rp[node], e1 = rp[node + 1];
    int e = e0;
    for (; e + 16 <= e1; e += 16) {
        int s[16];
#pragma unroll
        for (int j = 0; j < 16; ++j) s[j] = col[e + j];
        unsigned u[16];
#pragma unroll
        for (int j = 0; j < 16; ++j) u[j] = yv[(size_t)s[j] * 64 + c];
#pragma unroll
        for (int j = 0; j < 16; ++j) { a0 += lo_f(u[j]); a1 += hi_f(u[j]); }
    }
    for (; e + 8 <= e1; e += 8) {
        int s[8];
#pragma unroll
        for (int j = 0; j < 8; ++j) s[j] = col[e + j];
        unsigned u[8];
#pragma unroll
        for (int j = 0; j < 8; ++j) u[j] = yv[(size_t)s[j] * 64 + c];
#pragma unroll
        for (int j = 0; j < 8; ++j) { a0 += lo_f(u[j]); a1 += hi_f(u[j]); }
    }
    for (; e + 4 <= e1; e += 4) {
        int s0 = col[e], s1 = col[e + 1], s2 = col[e + 2], s3 = col[e + 3];
        unsigned u0 = yv[(size_t)s0 * 64 + c];
        unsigned u1 = yv[(size_t)s1 * 64 + c];
        unsigned u2 = yv[(size_t)s2 * 64 + c];
        unsigned u3 = yv[(size_t)s3 * 64 + c];
        a0 += (lo_f(u0) + lo_f(u1)) + (lo_f(u2) + lo_f(u3));
        a1 += (hi_f(u0) + hi_f(u1)) + (hi_f(u2) + hi_f(u3));
    }
    for (; e < e1; ++e) {
        unsigned u = yv[(size_t)col[e] * 64 + c];
        a0 += lo_f(u);
        a1 += hi_f(u);
    }
    float dn = dinv[node];
    unsigned o = ((unsigned)f2bf(a1 * dn) << 16) | (unsigned)f2bf(a0 * dn);
    outp[(size_t)node * 64 + c] = o;
}

// ---------------- MFMA GEMM + bias + relu (bf16 in, f32 acc) ----------------
// A [N][128] bf16 row-major (agg output); B = Wt bf16 pre-transposed global
// (32KB, L2-resident; no LDS staging, no barrier). 256 thr = 4 waves; each
// wave covers 32 rows x 128 cols.
// STORE_BF16=1: out_bf16 = bf16(dinv[r]*relu(acc+bias)); else out_f32 = relu.
// C/D mapping (HW-verified): col = lane&15, row = (lane>>4)*4 + reg.
// A/B k-ordering assumption is consistent between operands, so any bijective
// per-slot k-map cancels in the dot product.
template <int STORE_BF16>
__global__ __launch_bounds__(256) void k_mfma(const unsigned short* __restrict__ A,
                                              const unsigned short* __restrict__ Wt,
                                              const float* __restrict__ bias,
                                              float* __restrict__ out_f32,
                                              unsigned short* __restrict__ out_bf16,
                                              const float* __restrict__ dinv, int N) {
    int tid = threadIdx.x;
    int wv = tid >> 6, l = tid & 63;
    int lr = l & 15, lg = l >> 4;
    int r0 = blockIdx.x * 128 + wv * 32;

    f32x4 acc[2][8];
#pragma unroll
    for (int mi = 0; mi < 2; ++mi)
#pragma unroll
        for (int nf = 0; nf < 8; ++nf) acc[mi][nf] = (f32x4)(0.0f);

#pragma unroll
    for (int k0 = 0; k0 < 128; k0 += 32) {
        bf16x8 a[2];
#pragma unroll
        for (int mi = 0; mi < 2; ++mi) {
            int r = r0 + mi * 16 + lr;
            if (r >= N) r = N - 1;  // clamp: loads valid, stores guarded
            a[mi] = *reinterpret_cast<const bf16x8*>(&A[(size_t)r * 128 + k0 + lg * 8]);
        }
#pragma unroll
        for (int nf = 0; nf < 8; ++nf) {
            bf16x8 b = *reinterpret_cast<const bf16x8*>(
                &Wt[(size_t)(nf * 16 + lr) * 128 + k0 + lg * 8]);
            acc[0][nf] = __builtin_amdgcn_mfma_f32_16x16x32_bf16(a[0], b, acc[0][nf], 0, 0, 0);
            acc[1][nf] = __builtin_amdgcn_mfma_f32_16x16x32_bf16(a[1], b, acc[1][nf], 0, 0, 0);
        }
    }

    float bv[8];
#pragma unroll
    for (int nf = 0; nf < 8; ++nf) bv[nf] = bias[nf * 16 + lr];

#pragma unroll
    for (int mi = 0; mi < 2; ++mi) {
#pragma unroll
        for (int q = 0; q < 4; ++q) {
            int r = r0 + mi * 16 + lg * 4 + q;
            if (r < N) {
                float dv = 1.0f;
                if (STORE_BF16) dv = dinv[r];
#pragma unroll
                for (int nf = 0; nf < 8; ++nf) {
                    int ccol = nf * 16 + lr;
                    float vv = fmaxf(acc[mi][nf][q] + bv[nf], 0.0f);
                    if (STORE_BF16)
                        out_bf16[(size_t)r * 128 + ccol] = f2bf(vv * dv);
                    else
                        out_f32[(size_t)r * 128 + ccol] = vv;
                }
            }
        }
    }
}

// ---------------- launch ----------------

extern "C" void kernel_launch(void* const* d_in, const int* in_sizes, int n_in,
                              void* d_out, int out_size, void* d_ws, size_t ws_size,
                              hipStream_t stream) {
    const float* x  = (const float*)d_in[0];
    const int*   ei = (const int*)d_in[1];
    const float* W1 = (const float*)d_in[2];
    const float* b1 = (const float*)d_in[3];
    const float* W2 = (const float*)d_in[4];
    const float* b2 = (const float*)d_in[5];
    float* out = (float*)d_out;

    const int N = in_sizes[0] / D;
    const int E = in_sizes[1] / 2;
    const int* src = ei;
    const int* dst = ei + E;
    const int NBKT = (N + BNODES - 1) >> BSH;     // 391 for N=100000 (<= MAXB)
    const int CHUNK = (E + NCHUNK - 1) / NCHUNK;  // 3125 for E=1.6M

    char* w = (char*)d_ws;
    auto alloc = [&](size_t bytes) -> void* {
        void* p = (void*)w;
        w += (bytes + 255) & ~(size_t)255;
        return p;
    };
    float* dinv     = (float*)alloc((size_t)N * 4);
    int* rp         = (int*)alloc((size_t)(N + 1) * 4);
    int* cnts       = (int*)alloc((size_t)NBKT * NCHUNK * 4);  // ~0.8 MB
    int* btot       = (int*)alloc((size_t)NBKT * 4);
    int* bbase      = (int*)alloc((size_t)(NBKT + 1) * 4);
    unsigned* pairs = (unsigned*)alloc((size_t)E * 4);
    int* col        = (int*)alloc((size_t)E * 4);
    unsigned short* y    = (unsigned short*)alloc((size_t)N * D * 2);
    unsigned short* y2   = (unsigned short*)alloc((size_t)N * D * 2);
    unsigned short* Abuf = (unsigned short*)alloc((size_t)N * D * 2);
    unsigned short* Wt1  = (unsigned short*)alloc((size_t)D * D * 2);
    unsigned short* Wt2  = (unsigned short*)alloc((size_t)D * D * 2);

    k_hist<<<NCHUNK, 256, 0, stream>>>(dst, cnts, E, NBKT, CHUNK);
    k_chunksum<<<(NBKT + 3) / 4, 256, 0, stream>>>(cnts, btot, NBKT);
    k_bktscan<<<1, MAXB, 0, stream>>>(btot, bbase, NBKT);
    k_place<<<NCHUNK, 256, 0, stream>>>(src, dst, cnts, bbase, pairs, E, NBKT, CHUNK);
    k_build<<<NBKT, BNODES, 0, stream>>>(pairs, bbase, rp, dinv, col, N);
    k_wcvt<<<128, 256, 0, stream>>>(W1, W2, Wt1, Wt2);

    const int nchunk = N * (D / 4);
    const int aggblocks = (N + 3) / 4;
    const int gemmblocks = (N + 127) / 128;

    // layer 1: y = bf16(dinv*x); Abuf = agg(y); y2 = bf16(dinv*relu(Abuf@W1+b1))
    k_cvt<<<(nchunk + 255) / 256, 256, 0, stream>>>(x, dinv, y, nchunk);
    k_agg<<<aggblocks, 256, 0, stream>>>(y, (unsigned*)Abuf, col, rp, dinv, N);
    k_mfma<1><<<gemmblocks, 256, 0, stream>>>(Abuf, Wt1, b1, nullptr, y2, dinv, N);
    // layer 2: Abuf = agg(y2); out = relu(Abuf@W2+b2) f32
    k_agg<<<aggblocks, 256, 0, stream>>>(y2, (unsigned*)Abuf, col, rp, dinv, N);
    k_mfma<0><<<gemmblocks, 256, 0, stream>>>(Abuf, Wt2, b2, out, nullptr, dinv, N);
}

// Round 10
// 245.425 us; speedup vs baseline: 2.3777x; 1.0032x over previous
//
#include <hip/hip_runtime.h>

#define D 128
#define BSH 8                    // bucket = dst >> BSH (256 nodes per bucket)
#define BNODES (1 << BSH)
#define NCHUNK 512               // edge chunks; grid of place/hist kernels
#define MAXB 512                 // LDS bucket-array capacity (NBKT <= 512, N <= 131072)

typedef __attribute__((ext_vector_type(8))) __bf16 bf16x8;
typedef __attribute__((ext_vector_type(4))) float f32x4;

__device__ __forceinline__ unsigned short f2bf(float f) {
    unsigned int u = __float_as_uint(f);
    u += 0x7fffu + ((u >> 16) & 1u);  // round-to-nearest-even
    return (unsigned short)(u >> 16);
}
// bf16 pair packed in u32 (lo = even feature, hi = odd feature)
__device__ __forceinline__ float lo_f(unsigned u) { return __uint_as_float(u << 16); }
__device__ __forceinline__ float hi_f(unsigned u) { return __uint_as_float(u & 0xffff0000u); }

// ---------------- CSR build: contention-free counting sort ----------------
// pairs layout: (dstLocal<<24) | src   (needs N < 2^24, BNODES <= 256)

__global__ __launch_bounds__(256) void k_hist(const int* __restrict__ dst,
                                              int* __restrict__ cnts,
                                              int E, int nbkt, int chunk) {
    __shared__ int hist[MAXB];
    int c = blockIdx.x;
    int t = threadIdx.x;
    for (int i = t; i < nbkt; i += 256) hist[i] = 0;
    __syncthreads();
    int e0 = c * chunk, e1 = min(e0 + chunk, E);
    for (int e = e0 + t; e < e1; e += 256) atomicAdd(&hist[dst[e] >> BSH], 1);
    __syncthreads();
    for (int i = t; i < nbkt; i += 256) cnts[(size_t)i * NCHUNK + c] = hist[i];
}

// one wave per bucket: exclusive scan over the NCHUNK chunk-counts (in place),
// bucket total -> btot[b]. cnts reads/writes are lane-coalesced.
__global__ __launch_bounds__(256) void k_chunksum(int* __restrict__ cnts,
                                                  int* __restrict__ btot, int nbkt) {
    int b = blockIdx.x * 4 + (threadIdx.x >> 6);
    if (b >= nbkt) return;
    int l = threadIdx.x & 63;
    int carry = 0;
    for (int g = 0; g < NCHUNK; g += 64) {
        int v = cnts[(size_t)b * NCHUNK + g + l];
        int x = v;
#pragma unroll
        for (int off = 1; off < 64; off <<= 1) {
            int u = __shfl_up(x, off);
            if (l >= off) x += u;
        }
        cnts[(size_t)b * NCHUNK + g + l] = carry + x - v;  // exclusive
        carry += __shfl(x, 63);
    }
    if (l == 0) btot[b] = carry;
}

// one block: exclusive scan of bucket totals -> bbase[0..nbkt] (bbase[nbkt] = E)
__global__ __launch_bounds__(MAXB) void k_bktscan(const int* __restrict__ btot,
                                                  int* __restrict__ bbase, int nbkt) {
    __shared__ int s[MAXB];
    int t = threadIdx.x;
    int v = (t < nbkt) ? btot[t] : 0;
    s[t] = v;
    __syncthreads();
    for (int off = 1; off < MAXB; off <<= 1) {
        int u = (t >= off) ? s[t - off] : 0;
        __syncthreads();
        s[t] += u;
        __syncthreads();
    }
    if (t < nbkt) bbase[t + 1] = s[t];
    if (t == 0) bbase[0] = 0;
}

// chunk c: place packed pairs at precomputed per-(chunk,bucket) offsets;
// cursors advance via LDS atomics only.
__global__ __launch_bounds__(256) void k_place(const int* __restrict__ src,
                                               const int* __restrict__ dst,
                                               const int* __restrict__ cnts,
                                               const int* __restrict__ bbase,
                                               unsigned* __restrict__ pairs,
                                               int E, int nbkt, int chunk) {
    __shared__ int cur[MAXB];
    int c = blockIdx.x;
    int t = threadIdx.x;
    for (int i = t; i < nbkt; i += 256)
        cur[i] = bbase[i] + cnts[(size_t)i * NCHUNK + c];
    __syncthreads();
    int e0 = c * chunk, e1 = min(e0 + chunk, E);
    for (int e = e0 + t; e < e1; e += 256) {
        int d = dst[e];
        int p = atomicAdd(&cur[d >> BSH], 1);
        pairs[p] = ((unsigned)(d & (BNODES - 1)) << 24) | (unsigned)src[e];
    }
}

// one block per bucket: derive per-node degree (LDS count over pairs),
// wave-shfl scan (1 barrier) -> rp + dinv + local cursors, then scatter col
// within the bucket's contiguous region.
__global__ __launch_bounds__(BNODES) void k_build(const unsigned* __restrict__ pairs,
                                                  const int* __restrict__ bbase,
                                                  int* __restrict__ rp,
                                                  float* __restrict__ dinv,
                                                  int* __restrict__ col, int N) {
    __shared__ int cntL[BNODES];
    __shared__ int lcur[BNODES];
    __shared__ int wsum[BNODES / 64];
    int b = blockIdx.x;
    int n0 = b << BSH;
    int t = threadIdx.x;
    int lane = t & 63, wid = t >> 6;
    int e0 = bbase[b], e1 = bbase[b + 1];

    cntL[t] = 0;
    __syncthreads();
    for (int e = e0 + t; e < e1; e += BNODES)
        atomicAdd(&cntL[pairs[e] >> 24], 1);
    __syncthreads();
    int deg = cntL[t];
    // inclusive scan: wave-level shfl scan + cross-wave fixup
    int x = deg;
#pragma unroll
    for (int off = 1; off < 64; off <<= 1) {
        int u = __shfl_up(x, off);
        if (lane >= off) x += u;
    }
    if (lane == 63) wsum[wid] = x;
    __syncthreads();
    int wbase = 0;
#pragma unroll
    for (int i = 0; i < BNODES / 64; ++i) wbase += (i < wid) ? wsum[i] : 0;
    int rpv = e0 + wbase + x - deg;  // exclusive + bucket base
    lcur[t] = rpv;
    int node = n0 + t;
    if (node < N) {
        rp[node] = rpv;
        dinv[node] = rsqrtf((float)deg + 1.0f);  // +1 self-loop
        if (node == N - 1) rp[N] = e1;
    }
    __syncthreads();
    for (int e = e0 + t; e < e1; e += BNODES) {
        unsigned v = pairs[e];
        int p = atomicAdd(&lcur[v >> 24], 1);
        col[p] = (int)(v & 0x00FFFFFFu);
    }
}

// ---------------- x -> bf16, pre-scaled by dinv[row] ----------------
__global__ __launch_bounds__(256) void k_cvt(const float* __restrict__ x,
                                             const float* __restrict__ dinv,
                                             unsigned short* __restrict__ y, int nchunk) {
    int g = blockIdx.x * blockDim.x + threadIdx.x;
    if (g >= nchunk) return;
    int row = g >> 5;  // 32 chunks of 4 per 128-wide row
    float s = dinv[row];
    float4 v = reinterpret_cast<const float4*>(x)[g];
    ushort4 o;
    o.x = f2bf(v.x * s);
    o.y = f2bf(v.y * s);
    o.z = f2bf(v.z * s);
    o.w = f2bf(v.w * s);
    reinterpret_cast<ushort4*>(y)[g] = o;
}

// ---------------- W f32 -> Wt bf16 transposed (Wt[c][k] = W[k][c]) ----------
__global__ __launch_bounds__(256) void k_wcvt(const float* __restrict__ W1,
                                              const float* __restrict__ W2,
                                              unsigned short* __restrict__ Wt1,
                                              unsigned short* __restrict__ Wt2) {
    int idx = blockIdx.x * 256 + threadIdx.x;  // 0 .. 32767
    const float* W = (idx < 16384) ? W1 : W2;
    unsigned short* Wt = (idx < 16384) ? Wt1 : Wt2;
    int i = idx & 16383;
    int c = i >> 7, k = i & 127;
    Wt[(size_t)c * 128 + k] = f2bf(W[(size_t)k * 128 + c]);
}

// ---------------- normalized aggregation (gather, bf16 rows) ----------------
// outp[n] (bf16 pairs) = bf16( dinv[n] * ( y[n] + sum_{e in CSR(n)} y[col[e]] ) )
// One wave64 per node, 2-wave (128-thr) blocks: small straggle groups ->
// better block refill / occupancy. Lane owns a bf16 feature pair (u32);
// edge loop unrolled x16/x8/x4.
__global__ __launch_bounds__(128) void k_agg(const unsigned short* __restrict__ y,
                                             unsigned* __restrict__ outp,
                                             const int* __restrict__ col,
                                             const int* __restrict__ rp,
                                             const float* __restrict__ dinv, int n) {
    int node = blockIdx.x * 2 + (threadIdx.x >> 6);
    if (node >= n) return;
    int c = threadIdx.x & 63;  // feature pair index
    const unsigned* yv = reinterpret_cast<const unsigned*>(y);

    unsigned v = yv[(size_t)node * 64 + c];  // self loop
    float a0 = lo_f(v), a1 = hi_f(v);

    int e0 = rp[node], e1 = rp[node + 1];
    int e = e0;
    for (; e + 16 <= e1; e += 16) {
        int s[16];
#pragma unroll
        for (int j = 0; j < 16; ++j) s[j] = col[e + j];
        unsigned u[16];
#pragma unroll
        for (int j = 0; j < 16; ++j) u[j] = yv[(size_t)s[j] * 64 + c];
#pragma unroll
        for (int j = 0; j < 16; ++j) { a0 += lo_f(u[j]); a1 += hi_f(u[j]); }
    }
    for (; e + 8 <= e1; e += 8) {
        int s[8];
#pragma unroll
        for (int j = 0; j < 8; ++j) s[j] = col[e + j];
        unsigned u[8];
#pragma unroll
        for (int j = 0; j < 8; ++j) u[j] = yv[(size_t)s[j] * 64 + c];
#pragma unroll
        for (int j = 0; j < 8; ++j) { a0 += lo_f(u[j]); a1 += hi_f(u[j]); }
    }
    for (; e + 4 <= e1; e += 4) {
        int s0 = col[e], s1 = col[e + 1], s2 = col[e + 2], s3 = col[e + 3];
        unsigned u0 = yv[(size_t)s0 * 64 + c];
        unsigned u1 = yv[(size_t)s1 * 64 + c];
        unsigned u2 = yv[(size_t)s2 * 64 + c];
        unsigned u3 = yv[(size_t)s3 * 64 + c];
        a0 += (lo_f(u0) + lo_f(u1)) + (lo_f(u2) + lo_f(u3));
        a1 += (hi_f(u0) + hi_f(u1)) + (hi_f(u2) + hi_f(u3));
    }
    for (; e < e1; ++e) {
        unsigned u = yv[(size_t)col[e] * 64 + c];
        a0 += lo_f(u);
        a1 += hi_f(u);
    }
    float dn = dinv[node];
    unsigned o = ((unsigned)f2bf(a1 * dn) << 16) | (unsigned)f2bf(a0 * dn);
    outp[(size_t)node * 64 + c] = o;
}

// ---------------- MFMA GEMM + bias + relu (bf16 in, f32 acc) ----------------
// A [N][128] bf16 row-major (agg output); B = Wt bf16 pre-transposed global
// (32KB, L2-resident; no LDS staging, no barrier). 256 thr = 4 waves; each
// wave covers 32 rows x 128 cols.
// STORE_BF16=1: out_bf16 = bf16(dinv[r]*relu(acc+bias)); else out_f32 = relu.
// C/D mapping (HW-verified): col = lane&15, row = (lane>>4)*4 + reg.
// A/B k-ordering assumption is consistent between operands, so any bijective
// per-slot k-map cancels in the dot product.
template <int STORE_BF16>
__global__ __launch_bounds__(256) void k_mfma(const unsigned short* __restrict__ A,
                                              const unsigned short* __restrict__ Wt,
                                              const float* __restrict__ bias,
                                              float* __restrict__ out_f32,
                                              unsigned short* __restrict__ out_bf16,
                                              const float* __restrict__ dinv, int N) {
    int tid = threadIdx.x;
    int wv = tid >> 6, l = tid & 63;
    int lr = l & 15, lg = l >> 4;
    int r0 = blockIdx.x * 128 + wv * 32;

    f32x4 acc[2][8];
#pragma unroll
    for (int mi = 0; mi < 2; ++mi)
#pragma unroll
        for (int nf = 0; nf < 8; ++nf) acc[mi][nf] = (f32x4)(0.0f);

#pragma unroll
    for (int k0 = 0; k0 < 128; k0 += 32) {
        bf16x8 a[2];
#pragma unroll
        for (int mi = 0; mi < 2; ++mi) {
            int r = r0 + mi * 16 + lr;
            if (r >= N) r = N - 1;  // clamp: loads valid, stores guarded
            a[mi] = *reinterpret_cast<const bf16x8*>(&A[(size_t)r * 128 + k0 + lg * 8]);
        }
#pragma unroll
        for (int nf = 0; nf < 8; ++nf) {
            bf16x8 b = *reinterpret_cast<const bf16x8*>(
                &Wt[(size_t)(nf * 16 + lr) * 128 + k0 + lg * 8]);
            acc[0][nf] = __builtin_amdgcn_mfma_f32_16x16x32_bf16(a[0], b, acc[0][nf], 0, 0, 0);
            acc[1][nf] = __builtin_amdgcn_mfma_f32_16x16x32_bf16(a[1], b, acc[1][nf], 0, 0, 0);
        }
    }

    float bv[8];
#pragma unroll
    for (int nf = 0; nf < 8; ++nf) bv[nf] = bias[nf * 16 + lr];

#pragma unroll
    for (int mi = 0; mi < 2; ++mi) {
#pragma unroll
        for (int q = 0; q < 4; ++q) {
            int r = r0 + mi * 16 + lg * 4 + q;
            if (r < N) {
                float dv = 1.0f;
                if (STORE_BF16) dv = dinv[r];
#pragma unroll
                for (int nf = 0; nf < 8; ++nf) {
                    int ccol = nf * 16 + lr;
                    float vv = fmaxf(acc[mi][nf][q] + bv[nf], 0.0f);
                    if (STORE_BF16)
                        out_bf16[(size_t)r * 128 + ccol] = f2bf(vv * dv);
                    else
                        out_f32[(size_t)r * 128 + ccol] = vv;
                }
            }
        }
    }
}

// ---------------- launch ----------------

extern "C" void kernel_launch(void* const* d_in, const int* in_sizes, int n_in,
                              void* d_out, int out_size, void* d_ws, size_t ws_size,
                              hipStream_t stream) {
    const float* x  = (const float*)d_in[0];
    const int*   ei = (const int*)d_in[1];
    const float* W1 = (const float*)d_in[2];
    const float* b1 = (const float*)d_in[3];
    const float* W2 = (const float*)d_in[4];
    const float* b2 = (const float*)d_in[5];
    float* out = (float*)d_out;

    const int N = in_sizes[0] / D;
    const int E = in_sizes[1] / 2;
    const int* src = ei;
    const int* dst = ei + E;
    const int NBKT = (N + BNODES - 1) >> BSH;     // 391 for N=100000 (<= MAXB)
    const int CHUNK = (E + NCHUNK - 1) / NCHUNK;  // 3125 for E=1.6M

    char* w = (char*)d_ws;
    auto alloc = [&](size_t bytes) -> void* {
        void* p = (void*)w;
        w += (bytes + 255) & ~(size_t)255;
        return p;
    };
    float* dinv     = (float*)alloc((size_t)N * 4);
    int* rp         = (int*)alloc((size_t)(N + 1) * 4);
    int* cnts       = (int*)alloc((size_t)NBKT * NCHUNK * 4);  // ~0.8 MB
    int* btot       = (int*)alloc((size_t)NBKT * 4);
    int* bbase      = (int*)alloc((size_t)(NBKT + 1) * 4);
    unsigned* pairs = (unsigned*)alloc((size_t)E * 4);
    int* col        = (int*)alloc((size_t)E * 4);
    unsigned short* y    = (unsigned short*)alloc((size_t)N * D * 2);
    unsigned short* y2   = (unsigned short*)alloc((size_t)N * D * 2);
    unsigned short* Abuf = (unsigned short*)alloc((size_t)N * D * 2);
    unsigned short* Wt1  = (unsigned short*)alloc((size_t)D * D * 2);
    unsigned short* Wt2  = (unsigned short*)alloc((size_t)D * D * 2);

    k_hist<<<NCHUNK, 256, 0, stream>>>(dst, cnts, E, NBKT, CHUNK);
    k_chunksum<<<(NBKT + 3) / 4, 256, 0, stream>>>(cnts, btot, NBKT);
    k_bktscan<<<1, MAXB, 0, stream>>>(btot, bbase, NBKT);
    k_place<<<NCHUNK, 256, 0, stream>>>(src, dst, cnts, bbase, pairs, E, NBKT, CHUNK);
    k_build<<<NBKT, BNODES, 0, stream>>>(pairs, bbase, rp, dinv, col, N);
    k_wcvt<<<128, 256, 0, stream>>>(W1, W2, Wt1, Wt2);

    const int nchunk = N * (D / 4);
    const int aggblocks = (N + 1) / 2;
    const int gemmblocks = (N + 127) / 128;

    // layer 1: y = bf16(dinv*x); Abuf = agg(y); y2 = bf16(dinv*relu(Abuf@W1+b1))
    k_cvt<<<(nchunk + 255) / 256, 256, 0, stream>>>(x, dinv, y, nchunk);
    k_agg<<<aggblocks, 128, 0, stream>>>(y, (unsigned*)Abuf, col, rp, dinv, N);
    k_mfma<1><<<gemmblocks, 256, 0, stream>>>(Abuf, Wt1, b1, nullptr, y2, dinv, N);
    // layer 2: Abuf = agg(y2); out = relu(Abuf@W2+b2) f32
    k_agg<<<aggblocks, 128, 0, stream>>>(y2, (unsigned*)Abuf, col, rp, dinv, N);
    k_mfma<0><<<gemmblocks, 256, 0, stream>>>(Abuf, Wt2, b2, out, nullptr, dinv, N);
}